// Round 9
// baseline (9028.783 us; speedup 1.0000x reference)
//
#include <hip/hip_runtime.h>
#include <hip/hip_bf16.h>
#include <math.h>

#define NMIX 20

typedef unsigned short u16;
typedef unsigned int   u32;
typedef unsigned long long u64;
typedef __bf16 bfx8 __attribute__((ext_vector_type(8)));
typedef float  fx4  __attribute__((ext_vector_type(4)));

#define MFMA16(a,b,c) __builtin_amdgcn_mfma_f32_16x16x32_bf16((a),(b),(c),0,0,0)

__device__ __forceinline__ float sigm(float x){ return 1.0f/(1.0f+__expf(-x)); }
__device__ __forceinline__ u16 f2bf(float x){ u32 u=__float_as_uint(x); return (u16)((u + 0x7fffu + ((u>>16)&1u))>>16); }
__device__ __forceinline__ float bf2f(u16 h){ return __uint_as_float(((u32)h)<<16); }
__device__ __forceinline__ u32 packh(float v){ u16 hh=f2bf(v); return ((u32)hh<<16) | (u32)f2bf(v - bf2f(hh)); }

__device__ __forceinline__ u64 ald64(const u64* p){ return __hip_atomic_load(p,__ATOMIC_RELAXED,__HIP_MEMORY_SCOPE_AGENT); }
__device__ __forceinline__ void ast32(u32* p,u32 v){ __hip_atomic_store(p,v,__ATOMIC_RELAXED,__HIP_MEMORY_SCOPE_AGENT); }

// consumers: relaxed poll (serviced coherently at LLC, no cache maintenance) + compiler fence
__device__ __forceinline__ void poll(const int* f,int mask,int tok){
  const int idx=(threadIdx.x&63)&mask;
  for(;;){ int v=__hip_atomic_load(f+idx,__ATOMIC_RELAXED,__HIP_MEMORY_SCOPE_AGENT);
    if(__all(v>=tok)) break; __builtin_amdgcn_s_sleep(1); }
  __atomic_signal_fence(__ATOMIC_SEQ_CST);
}

// ---------------- prep: split fp32 weight [K][Nsrc] -> transposed bf16 hi/lo [Nout][K] ----------------
__global__ __launch_bounds__(256) void prep_split_T(const float* __restrict__ src,
                                                    u16* dhi, u16* dlo, int K, int Nsrc, int Nout) {
    int idx = blockIdx.x * 256 + threadIdx.x;
    if (idx >= Nout * K) return;
    int n = idx / K, k = idx - n * K;
    float v = (n < Nsrc) ? src[k * Nsrc + n] : 0.0f;
    u16 hh = f2bf(v);
    dhi[idx] = hh;
    dlo[idx] = f2bf(v - bf2f(hh));
}

// ---------------- persistent encoder ----------------
// grid 128 = dir(2) x jx(4, 64 h-cols) x rt(16, 32 rows). Batched far-load A staging.
__global__ __launch_bounds__(256,1) void enc_persist(
    const float* __restrict__ x,
    const float* __restrict__ Wih_f, const float* __restrict__ b_f,
    const float* __restrict__ Wih_b, const float* __restrict__ b_b,
    const u16* __restrict__ encT, u32* __restrict__ he32, int* __restrict__ encF)
{
    __shared__ u16 AH[32*256];    // 16KB, full K
    __shared__ u16 AL[32*256];    // 16KB
    __shared__ float xL[160];

    const int bx=blockIdx.x, dir=bx>>6, jx=(bx>>4)&3, rt=bx&15;
    const int j0=jx*64, row0=rt*32;
    int* ef = encF + (dir*16+rt)*32;
    const u16* wTh = encT + dir*524288;
    const u16* wTl = wTh + 262144;
    const float* Wih = dir? Wih_b : Wih_f;
    const float* bias= dir? b_b : b_f;

    const int tid=threadIdx.x, wv=tid>>6, lane=tid&63;
    const int ln15=lane&15, kq=lane>>4;
    const int jc = wv*16+ln15;
    const int arow = tid>>3, agran = tid&7;

    float wih[5][4], bi4[4];
#pragma unroll
    for(int g=0; g<4; ++g){
        bi4[g] = bias[g*256 + j0 + jc];
#pragma unroll
        for(int i=0;i<5;++i) wih[i][g] = Wih[i*1024 + g*256 + j0 + jc];
    }
    float c16[2][4] = {};

#pragma unroll 1
    for (int t=0; t<=200; ++t) {
      const int pb=t&1;
      const u32* hp = he32 + (pb*2+dir)*131072;
      u32* hn = he32 + ((pb^1)*2+dir)*131072;
      const int ts = dir ? 200-t : t;
      for (int i = tid; i < 160; i += 256) xL[i] = x[ts*2560 + row0*5 + i];
      poll(ef, 3, t);

      u64 q[16];
      {
        const u64* s = (const u64*)(hp + (size_t)(row0+arow)*256);
#pragma unroll
        for(int i=0;i<16;++i) q[i] = ald64(s + i*8 + agran);
      }
#pragma unroll
      for(int i=0;i<16;++i){
        u32 pe=(u32)q[i], po=(u32)(q[i]>>32);
        int ui = i*8 + agran;
        int off = arow*256 + (((ui>>2) ^ (arow&7))<<3) + (ui&3)*2;
        *(u32*)&AH[off] = (pe>>16) | (po & 0xffff0000u);
        *(u32*)&AL[off] = (pe & 0xffffu) | (po<<16);
      }
      __syncthreads();

      fx4 acc[2][4] = {};
#pragma unroll
      for(int ch=0; ch<8; ++ch){
        bfx8 ah[2], al[2];
#pragma unroll
        for(int rta=0;rta<2;++rta){
          int off = (rta*16+ln15)*256 + (((ch*4+kq)^(ln15&7))<<3);
          ah[rta]=*(const bfx8*)&AH[off]; al[rta]=*(const bfx8*)&AL[off];
        }
#pragma unroll
        for(int nt=0;nt<4;++nt){
          size_t bo=(size_t)(nt*256 + j0 + jc)*256 + ch*32 + kq*8;
          bfx8 bh=*(const bfx8*)&wTh[bo], bl=*(const bfx8*)&wTl[bo];
#pragma unroll
          for(int rta=0;rta<2;++rta){
            acc[rta][nt]=MFMA16(ah[rta],bh,acc[rta][nt]);
            acc[rta][nt]=MFMA16(ah[rta],bl,acc[rta][nt]);
            acc[rta][nt]=MFMA16(al[rta],bh,acc[rta][nt]);}}
      }
#pragma unroll
      for(int rta=0;rta<2;++rta)
#pragma unroll
      for(int r2=0;r2<4;++r2){
        const int rl=rta*16+kq*4+r2;
        float gv[4];
#pragma unroll
        for(int g=0;g<4;++g){
          float s2=acc[rta][g][r2]+bi4[g];
#pragma unroll
          for(int i=0;i<5;++i) s2+=xL[rl*5+i]*wih[i][g];
          gv[g]=s2;}
        float cv=c16[rta][r2];
        cv=sigm(gv[1])*cv+sigm(gv[0])*tanhf(gv[2]);
        c16[rta][r2]=cv;
        float hv2=sigm(gv[3])*tanhf(cv);
        ast32(&hn[(row0+rl)*256 + j0 + jc], packh(hv2));
      }
      __syncthreads();   // drains vmcnt (h stores acked) before flag; also guards AH/AL reuse
      if(tid==0) __hip_atomic_store(&ef[jx], t+1, __ATOMIC_RELAXED, __HIP_MEMORY_SCOPE_AGENT);
    }
}

// ---------------- latent 1: mean/logvar/z ----------------
__global__ __launch_bounds__(256) void latent1(
    const u32* __restrict__ he32,
    const float* __restrict__ W_mu, const float* __restrict__ b_mu,
    const float* __restrict__ W_lv, const float* __restrict__ b_lv,
    const float* __restrict__ eps, float* z, float* out)
{
    __shared__ float hs[16 * 512];
    const int row0 = blockIdx.x * 16;
    const int tid = threadIdx.x;
    const u32* hf = he32 + 2*131072;   // final buffer = buf1, dir0
    const u32* hb = he32 + 3*131072;   // buf1, dir1
    for (int i = tid; i < 8192; i += 256) {
        int r = i >> 9, col = i & 511;
        int gi = (row0 + r) * 256;
        u32 p = (col < 256) ? hf[gi + col] : hb[gi + (col - 256)];
        hs[i] = bf2f((u16)(p >> 16)) + bf2f((u16)p);
    }
    __syncthreads();
    for (int p = tid; p < 2048; p += 256) {
        int r = p >> 7, cc = p & 127;
        const float* hr = hs + r * 512;
        float m = 0, lv = 0;
#pragma unroll 8
        for (int k = 0; k < 512; ++k) {
            float hv = hr[k];
            m  += hv * W_mu[k * 128 + cc];
            lv += hv * W_lv[k * 128 + cc];
        }
        m += b_mu[cc]; lv += b_lv[cc];
        int b = row0 + r;
        out[512002 + b * 128 + cc] = m;
        out[577538 + b * 128 + cc] = lv;
        z[b * 128 + cc] = m + __expf(0.5f * lv) * eps[b * 128 + cc];
    }
}

// ---------------- latent 2: h0 (packed) / c0; zpre ----------------
__global__ __launch_bounds__(256) void latent2(
    const float* __restrict__ z, const float* __restrict__ W_fc, const float* __restrict__ b_fc,
    const float* __restrict__ dWih, const float* __restrict__ dec_b,
    u32* __restrict__ hd32, float* c_d, float* zpre)
{
    __shared__ float zs[16 * 128];
    const int row0 = blockIdx.y * 16;
    const int tid = threadIdx.x;
    {
        float4* dst = (float4*)zs;
        const float4* src = (const float4*)(z + row0 * 128);
        for (int i = tid; i < 512; i += 256) dst[i] = src[i];
    }
    __syncthreads();
    const int colbase = blockIdx.x * 128;
    for (int p = tid; p < 16 * 128; p += 256) {
        int r = p >> 7, cl = p & 127;
        int col = colbase + cl;
        const float* zr = zs + r * 128;
        int b = row0 + r;
        if (col < 1024) {
            float acc = 0;
#pragma unroll 8
            for (int k = 0; k < 128; ++k) acc += zr[k] * W_fc[k * 1024 + col];
            float v = tanhf(acc + b_fc[col]);
            if (col < 512) hd32[b * 512 + col] = packh(v);
            else           c_d[b * 512 + (col - 512)] = v;
        } else {
            int n = col - 1024;
            float acc = 0;
#pragma unroll 8
            for (int k = 0; k < 128; ++k) acc += zr[k] * dWih[(5 + k) * 2048 + n];
            zpre[b * 2048 + n] = acc + dec_b[n];
        }
    }
}

// ---------------- persistent decoder: FUSED cell + redundant y head ----------------
// grid 128 = jx(8, 64 h-cols) x rt(16, 32 rows). Every block: cell GEMM + full 128-col y GEMM
// + local mixture (redundant) -> sxs stays in LDS. ONE flag hop per step. jx0 writes outputs.
__global__ __launch_bounds__(256,1) void dec_persist(
    const float* __restrict__ x, const int* __restrict__ N_s,
    const float* __restrict__ dec_Wih, const float* __restrict__ b_out,
    const u16* __restrict__ decT, const u16* __restrict__ woutT,
    const float* __restrict__ zpre, const float* __restrict__ c_init,
    u32* __restrict__ hd32, float* __restrict__ out, int* __restrict__ decHF)
{
    __shared__ u16 AH[32*256];        // 16KB, half-K batch
    __shared__ u16 AL[32*256];        // 16KB
    __shared__ float yL[32*132];      // full y head, all blocks
    __shared__ float sxsL[32*8];
    __shared__ float xtL[160];
    __shared__ int  lenL[32];
    __shared__ float redL[64];

    const int bx=blockIdx.x, jx=bx>>4, rt=bx&15;
    const int j0=jx*64, row0=rt*32;
    int* hF = decHF + rt*32;
    const u16* wHh = decT;
    const u16* wHl = decT + 1048576;
    const u16* wOh = woutT;
    const u16* wOl = woutT + 65536;

    const int tid=threadIdx.x, wv=tid>>6, lane=tid&63;
    const int ln15=lane&15, kq=lane>>4;
    const int jc = wv*16+ln15;
    const int arow = tid>>3, agran = tid&7;

    auto LOADA=[&](const u32* hp, int b, u64* q){
        const u64* s = (const u64*)(hp + (size_t)(row0+arow)*512 + b*256);
#pragma unroll
        for(int i=0;i<16;++i) q[i] = ald64(s + i*8 + agran);
    };
    auto WRITEA=[&](const u64* q){
#pragma unroll
        for(int i=0;i<16;++i){
            u32 pe=(u32)q[i], po=(u32)(q[i]>>32);
            int ui = i*8 + agran;
            int off = arow*256 + (((ui>>2) ^ (arow&7))<<3) + (ui&3)*2;
            *(u32*)&AH[off] = (pe>>16) | (po & 0xffff0000u);
            *(u32*)&AL[off] = (pe & 0xffffu) | (po<<16);
        }
    };

    // per-thread constants
    float dw[5][4], zp[2][4][4], c16[2][4], bo2[2];
#pragma unroll
    for(int g=0;g<4;++g)
#pragma unroll
    for(int i=0;i<5;++i) dw[i][g] = dec_Wih[i*2048 + g*512 + j0 + jc];
#pragma unroll
    for(int rta=0;rta<2;++rta)
#pragma unroll
    for(int r2=0;r2<4;++r2){
        const int R = row0 + rta*16 + kq*4 + r2;
        c16[rta][r2] = c_init[(size_t)R*512 + j0 + jc];
#pragma unroll
        for(int g=0;g<4;++g) zp[rta][r2][g] = zpre[(size_t)R*2048 + g*512 + j0 + jc];
    }
#pragma unroll
    for(int nt=0;nt<2;++nt){ int col=wv*32+nt*16+ln15; bo2[nt] = (col<123)? b_out[col] : 0.0f; }
    if (tid < 32) lenL[tid] = N_s[row0 + tid];
    for (int i = tid; i < 256; i += 256) sxsL[i] = ((i&7)==2) ? 1.0f : 0.0f;   // stroke0
    __syncthreads();

#pragma unroll 1
    for (int s = 0; s <= 199; ++s) {
        const bool do_cell = (s < 199);
        const bool do_y = (s > 0);
        if (s == 199 && jx != 0) return;    // only jx0 needs the final y (stroke 198 + losses)
        const u32* hp = hd32 + (s&1)*262144;
        u32* hn = hd32 + ((s&1)^1)*262144;
        for (int i = tid; i < 160; i += 256) xtL[i] = x[s*2560 + row0*5 + i];
        poll(hF, 7, s);

        fx4 acc[2][4] = {};
        fx4 accy[2][2] = {};
        u64 q[16], q2[16];
        LOADA(hp,0,q);
        WRITEA(q); __syncthreads();
        LOADA(hp,1,q2);                        // batch-1 in flight under batch-0 compute
#pragma unroll
        for(int b=0;b<2;++b){
            if(b){ __syncthreads(); WRITEA(q2); __syncthreads(); }
#pragma unroll
            for(int ch=0; ch<8; ++ch){
                bfx8 ah[2], al[2];
#pragma unroll
                for(int rta=0;rta<2;++rta){
                    int off = (rta*16+ln15)*256 + (((ch*4+kq)^(ln15&7))<<3);
                    ah[rta]=*(const bfx8*)&AH[off]; al[rta]=*(const bfx8*)&AL[off];
                }
                if (do_cell) {
#pragma unroll
                    for(int nt=0;nt<4;++nt){
                        size_t bo=(size_t)(nt*512 + j0 + jc)*512 + b*256 + ch*32 + kq*8;
                        bfx8 bh=*(const bfx8*)&wHh[bo], bl=*(const bfx8*)&wHl[bo];
#pragma unroll
                        for(int rta=0;rta<2;++rta){
                            acc[rta][nt]=MFMA16(ah[rta],bh,acc[rta][nt]);
                            acc[rta][nt]=MFMA16(ah[rta],bl,acc[rta][nt]);
                            acc[rta][nt]=MFMA16(al[rta],bh,acc[rta][nt]);}}
                }
                if (do_y) {
#pragma unroll
                    for(int nt=0;nt<2;++nt){
                        size_t bo=(size_t)(wv*32 + nt*16 + ln15)*512 + b*256 + ch*32 + kq*8;
                        bfx8 bh=*(const bfx8*)&wOh[bo], bl=*(const bfx8*)&wOl[bo];
#pragma unroll
                        for(int rta=0;rta<2;++rta){
                            accy[rta][nt]=MFMA16(ah[rta],bh,accy[rta][nt]);
                            accy[rta][nt]=MFMA16(ah[rta],bl,accy[rta][nt]);
                            accy[rta][nt]=MFMA16(al[rta],bh,accy[rta][nt]);}}
                }
            }
        }
        __syncthreads();    // GEMM reads of AH/AL done; xtL visible; prev sxsL reads done

        if (do_y) {
#pragma unroll
            for(int rta=0;rta<2;++rta)
#pragma unroll
            for(int nt=0;nt<2;++nt)
#pragma unroll
            for(int r2=0;r2<4;++r2)
                yL[(rta*16+kq*4+r2)*132 + wv*32+nt*16+ln15] = accy[rta][nt][r2] + bo2[nt];
            __syncthreads();
            {
                const int row = tid>>3, sub = tid&7;
                const float* yr = &yL[row*132];
                const float dxv = xtL[row*5], dyv = xtL[row*5+1];
                float pm = -1e30f;
                for (int cg = sub; cg < NMIX; cg += 8) pm = fmaxf(pm, yr[cg*6]);
                pm = fmaxf(pm, __shfl_xor(pm, 1));
                pm = fmaxf(pm, __shfl_xor(pm, 2));
                pm = fmaxf(pm, __shfl_xor(pm, 4));
                float S = 0, gp = 0, gx = 0, gy = 0;
                for (int cg = sub; cg < NMIX; cg += 8) {
                    float ph = yr[cg*6], mux = yr[cg*6+1], muy = yr[cg*6+2];
                    float ssx = __expf(yr[cg*6+3]), ssy = __expf(yr[cg*6+4]);
                    float rho = tanhf(yr[cg*6+5]);
                    float e = __expf(ph - pm);
                    float zx = (dxv - mux)/ssx, zy = (dyv - muy)/ssy;
                    float om = 1.0f - rho*rho;
                    float pdf = __expf(-(zx*zx + zy*zy - 2.0f*rho*zx*zy)/(2.0f*om))
                                * (0.15915494309189535f/(ssx*ssy*sqrtf(om)));
                    S += e; gp += e*pdf; gx += e*mux; gy += e*muy;
                }
#pragma unroll
                for (int off = 1; off < 8; off <<= 1) {
                    S += __shfl_xor(S, off); gp += __shfl_xor(gp, off);
                    gx += __shfl_xor(gx, off); gy += __shfl_xor(gy, off);
                }
                if (sub == 0) {
                    const int b = row0 + row;
                    float q0v = yr[120], q1v = yr[121], q2v = yr[122];
                    int len = lenL[row];
                    int am = 0; float bv = q0v;
                    if (q1v > bv) { bv = q1v; am = 1; }
                    if (q2v > bv) { bv = q2v; am = 2; }
                    float s0,s1,s2,s3,s4;
                    if (s > len) { s0=s1=s2=s3=0.0f; s4=1.0f; }
                    else { s0=gx/S; s1=gy/S; s2=(am==0); s3=(am==1); s4=(am==2); }
                    sxsL[row*8+0]=s0; sxsL[row*8+1]=s1; sxsL[row*8+2]=s2;
                    sxsL[row*8+3]=s3; sxsL[row*8+4]=s4;
                    if (jx == 0) {
                        float qm = fmaxf(q0v, fmaxf(q1v, q2v));
                        float lse = qm + logf(__expf(q0v-qm)+__expf(q1v-qm)+__expf(q2v-qm));
                        float pl = -(xtL[row*5+2]*(q0v-lse) + xtL[row*5+3]*(q1v-lse) + xtL[row*5+4]*(q2v-lse));
                        float ol = (s < len) ? -logf(gp/S + 1e-6f) : 0.0f;
                        float* so = out + (s-1)*2560 + b*5;
                        so[0]=s0; so[1]=s1; so[2]=s2; so[3]=s3; so[4]=s4;
                        redL[row] = pl; redL[32+row] = ol;
                    }
                }
            }
            __syncthreads();    // sxsL visible for epilogue
            if (jx == 0 && tid == 0) {
                float spl=0, sol=0;
                for (int r=0;r<32;++r){ spl+=redL[r]; sol+=redL[32+r]; }
                atomicAdd(out + 512001, spl * (1.0f/102400.0f));
                atomicAdd(out + 512000, sol * (1.0f/102400.0f));
            }
        }

        if (do_cell) {
#pragma unroll
            for(int rta=0;rta<2;++rta)
#pragma unroll
            for(int r2=0;r2<4;++r2){
                const int rl=rta*16+kq*4+r2;
                float gv[4];
#pragma unroll
                for(int g=0;g<4;++g){
                    float s2=acc[rta][g][r2]+zp[rta][r2][g];
#pragma unroll
                    for(int i=0;i<5;++i) s2+=sxsL[rl*8+i]*dw[i][g];
                    gv[g]=s2;}
                float cv=c16[rta][r2];
                cv=sigm(gv[1])*cv+sigm(gv[0])*tanhf(gv[2]);
                c16[rta][r2]=cv;
                float hv2=sigm(gv[3])*tanhf(cv);
                ast32(&hn[(size_t)(row0+rl)*512 + j0 + jc], packh(hv2));
            }
            __syncthreads();    // h stores drained (vmcnt) before flag; guards AH/AL + sxsL reuse
            if(tid==0) __hip_atomic_store(&hF[jx], s+1, __ATOMIC_RELAXED, __HIP_MEMORY_SCOPE_AGENT);
        }
    }
}

extern "C" void kernel_launch(void* const* d_in, const int* in_sizes, int n_in,
                              void* d_out_, int out_size, void* d_ws, size_t ws_size,
                              hipStream_t stream) {
    const float* x         = (const float*)d_in[0];
    const int*   N_s       = (const int*)  d_in[1];
    const float* eps       = (const float*)d_in[2];
    const float* enc_Wih_f = (const float*)d_in[3];
    const float* enc_Whh_f = (const float*)d_in[4];
    const float* enc_b_f   = (const float*)d_in[5];
    const float* enc_Wih_b = (const float*)d_in[6];
    const float* enc_Whh_b = (const float*)d_in[7];
    const float* enc_b_b   = (const float*)d_in[8];
    const float* W_mu      = (const float*)d_in[9];
    const float* b_mu      = (const float*)d_in[10];
    const float* W_logvar  = (const float*)d_in[11];
    const float* b_logvar  = (const float*)d_in[12];
    const float* W_fc_in   = (const float*)d_in[13];
    const float* b_fc_in   = (const float*)d_in[14];
    const float* dec_Wih   = (const float*)d_in[15];
    const float* dec_Whh   = (const float*)d_in[16];
    const float* dec_b     = (const float*)d_in[17];
    const float* W_out     = (const float*)d_in[18];
    const float* b_out     = (const float*)d_in[19];
    float* out = (float*)d_out_;
    float* ws  = (float*)d_ws;

    float* c_d   = ws + 0;                      // 262144
    float* zpre  = ws + 262144;                 // 1048576
    float* z     = ws + 1310720;                // 65536
    int*   flags = (int*)(ws + 1380352);        // 2048: encF 1024 | decHF 512
    u32*   hd32  = (u32*)(ws + 1382400);        // 2 x 262144
    u32*   he32  = (u32*)(ws + 1906688);        // 4 x 131072 (buf x dir)
    u16*   encT  = (u16*)(ws + 2430976);        // 4 x 262144 u16
    u16*   decT  = (u16*)(ws + 2955264);        // 2 x 1048576 u16
    u16*   woutT = (u16*)(ws + 4003840);        // 2 x 65536 u16
    int* encF  = flags;
    int* decHF = flags + 1024;

    hipMemsetAsync(he32, 0, 262144 * sizeof(u32), stream);         // h(0) both dirs, buf0
    hipMemsetAsync(flags, 0, 2048 * sizeof(int), stream);
    hipMemsetAsync(out + 509440, 0, 2562 * sizeof(float), stream); // stroke row 199 + losses

    prep_split_T<<<1024, 256, 0, stream>>>(enc_Whh_f, encT,          encT + 262144,  256, 1024, 1024);
    prep_split_T<<<1024, 256, 0, stream>>>(enc_Whh_b, encT + 524288, encT + 786432,  256, 1024, 1024);
    prep_split_T<<<4096, 256, 0, stream>>>(dec_Whh,   decT,          decT + 1048576, 512, 2048, 2048);
    prep_split_T<<<256,  256, 0, stream>>>(W_out,     woutT,         woutT + 65536,  512, 123, 128);

    enc_persist<<<128, 256, 0, stream>>>(x, enc_Wih_f, enc_b_f, enc_Wih_b, enc_b_b, encT, he32, encF);
    latent1<<<32, 256, 0, stream>>>(he32, W_mu, b_mu, W_logvar, b_logvar, eps, z, out);
    latent2<<<dim3(24, 32), 256, 0, stream>>>(z, W_fc_in, b_fc_in, dec_Wih, dec_b, hd32, c_d, zpre);
    dec_persist<<<128, 256, 0, stream>>>(x, N_s, dec_Wih, b_out, decT, woutT, zpre, c_d,
                                         hd32, out, decHF);
}